// Round 13
// baseline (141.187 us; speedup 1.0000x reference)
//
#include <hip/hip_runtime.h>

#define NNODES 50000
#define NEDGES 800000
#define IN_F 64
#define HID 128
#define OUT_F 64
#define STRIDE 64    // padded CSR row capacity (mean deg 16; P(>64) ~ 0)
#define NPB 256      // nodes per bucket (power of 2: bucket = node >> 8)
#define NB 196       // ceil(50000/256) buckets
#define BCAP 5120    // per-bucket edge capacity (mean 4096, +16 sigma)
#define CHUNK 2048   // edges per bucketing workgroup

static __device__ __forceinline__ unsigned short f2bf(float f) {
    unsigned int u = __float_as_uint(f);
    u = u + 0x7FFFu + ((u >> 16) & 1u);   // round-to-nearest-even
    return (unsigned short)(u >> 16);
}
static __device__ __forceinline__ float bf2f(unsigned short h) {
    return __uint_as_float((unsigned int)h << 16);
}
// packed-u32 bf16 pair unpack: LO = element 2i, HI = element 2i+1
#define BLO(p) __uint_as_float((p) << 16)
#define BHI(p) __uint_as_float((p) & 0xffff0000u)
static __device__ __forceinline__ unsigned int packbf(float a, float b) {
    return (unsigned int)f2bf(a) | ((unsigned int)f2bf(b) << 16);
}

// ---------------- bucketed CSR build (no per-edge global atomics) ----------------

__global__ __launch_bounds__(256) void bucket_edges_k(const int* __restrict__ src,
                                                      const int* __restrict__ dst,
                                                      int* __restrict__ bcur_d,
                                                      int* __restrict__ bcur_s,
                                                      unsigned int* __restrict__ bed,
                                                      unsigned char* __restrict__ bes) {
    __shared__ int cntd[NB], cnts[NB], based_[NB], bases_[NB];
    const int tid = threadIdx.x;
    const int e0 = blockIdx.x * CHUNK;
    for (int i = tid; i < NB; i += 256) { cntd[i] = 0; cnts[i] = 0; }
    __syncthreads();
    for (int k = tid; k < CHUNK; k += 256) {
        int e = e0 + k;
        if (e < NEDGES) {
            atomicAdd(&cntd[dst[e] >> 8], 1);
            atomicAdd(&cnts[src[e] >> 8], 1);
        }
    }
    __syncthreads();
    for (int i = tid; i < NB; i += 256) {
        based_[i] = cntd[i] ? atomicAdd(&bcur_d[i], cntd[i]) : 0;
        bases_[i] = cnts[i] ? atomicAdd(&bcur_s[i], cnts[i]) : 0;
        cntd[i] = 0; cnts[i] = 0;
    }
    __syncthreads();
    for (int k = tid; k < CHUNK; k += 256) {
        int e = e0 + k;
        if (e < NEDGES) {
            int s = src[e], d = dst[e];
            int bd = d >> 8, bs = s >> 8;
            int pd = based_[bd] + atomicAdd(&cntd[bd], 1);
            if (pd < BCAP) bed[(size_t)bd * BCAP + pd] = ((unsigned)s << 8) | (unsigned)(d & 255);
            int ps = bases_[bs] + atomicAdd(&cnts[bs], 1);
            if (ps < BCAP) bes[(size_t)bs * BCAP + ps] = (unsigned char)(s & 255);
        }
    }
}

// One WG per bucket (256 nodes): padded CSR via LDS cursors, degrees, norms,
// and the pre-scaled feature table xbf = bf16(feat * sc) (streaming).
__global__ __launch_bounds__(256) void csr_norm_xpre(const int* __restrict__ bcur_d,
                                                     const int* __restrict__ bcur_s,
                                                     const unsigned int* __restrict__ bed,
                                                     const unsigned char* __restrict__ bes,
                                                     const float* __restrict__ feat,
                                                     int* __restrict__ padded,
                                                     int* __restrict__ deg_in,
                                                     float* __restrict__ norm_in,
                                                     float* __restrict__ sc,
                                                     unsigned short* __restrict__ xbf) {
    __shared__ int curs[NPB];
    __shared__ int hist[NPB];
    __shared__ float scl[NPB];
    const int b = blockIdx.x;
    const int tid = threadIdx.x;
    const int base = b << 8;
    curs[tid] = 0; hist[tid] = 0;
    __syncthreads();
    const int nd = min(bcur_d[b], BCAP);
    const int ns = min(bcur_s[b], BCAP);
    const unsigned int* ed = bed + (size_t)b * BCAP;
    const unsigned char* es = bes + (size_t)b * BCAP;
    for (int k = tid; k < nd; k += 256) {
        unsigned v = ed[k];
        int s = (int)(v >> 8), dl = (int)(v & 255u);
        int pos = atomicAdd(&curs[dl], 1);
        if (pos < STRIDE) padded[((size_t)(base + dl) << 6) + pos] = s;
    }
    for (int k = tid; k < ns; k += 256)
        atomicAdd(&hist[(int)es[k]], 1);
    __syncthreads();
    int node = base + tid;
    if (node < NNODES) {
        int din = curs[tid];
        int dout = hist[tid];
        deg_in[node] = din;
        if (din < 1) din = 1;
        if (dout < 1) dout = 1;
        float ni = 1.0f / sqrtf((float)din);
        float no = 1.0f / sqrtf((float)dout);
        norm_in[node] = ni;
        float s_ = ni * no;
        sc[node] = s_;
        scl[tid] = s_;
    } else {
        scl[tid] = 0.0f;
    }
    __syncthreads();
    // xbf for this WG's 256 nodes: float4 read -> ushort4 (bf16 RNE) write
    const float4* f4 = (const float4*)feat;
    for (int i = tid; i < NPB * 16; i += 256) {
        int nl = i >> 4;
        int gn = base + nl;
        if (gn < NNODES) {
            float4 v = f4[(size_t)gn * 16 + (i & 15)];
            float s_ = scl[nl];
            ushort4 o;
            o.x = f2bf(v.x * s_); o.y = f2bf(v.y * s_);
            o.z = f2bf(v.z * s_); o.w = f2bf(v.w * s_);
            *(ushort4*)&xbf[((size_t)gn << 6) + (size_t)(i & 15) * 4] = o;
        }
    }
}

// ---------------- aggregation (gather, 16 lanes/node) ----------------

__global__ __launch_bounds__(256) void agg_xpre(const int* __restrict__ deg_in,
                                                const int* __restrict__ padded,
                                                const unsigned short* __restrict__ xbf,
                                                float* __restrict__ aggout) {
    const int tid = threadIdx.x;
    const int node = blockIdx.x * 16 + (tid >> 4);
    const int sl = tid & 15;            // 4-feature slice
    if (node >= NNODES) return;
    const int* row = padded + ((size_t)node << 6);
    int n = deg_in[node]; if (n > STRIDE) n = STRIDE;
    float x0 = 0.f, y0 = 0.f, z0 = 0.f, w0 = 0.f;
    float x1 = 0.f, y1 = 0.f, z1 = 0.f, w1 = 0.f;
    int k = 0;
    for (; k + 2 <= n; k += 2) {
        int s0 = row[k], s1 = row[k + 1];
        ushort4 a = *(const ushort4*)&xbf[((size_t)s0 << 6) + (size_t)sl * 4];
        ushort4 b = *(const ushort4*)&xbf[((size_t)s1 << 6) + (size_t)sl * 4];
        x0 += bf2f(a.x); y0 += bf2f(a.y); z0 += bf2f(a.z); w0 += bf2f(a.w);
        x1 += bf2f(b.x); y1 += bf2f(b.y); z1 += bf2f(b.z); w1 += bf2f(b.w);
    }
    if (k < n) {
        ushort4 a = *(const ushort4*)&xbf[((size_t)row[k] << 6) + (size_t)sl * 4];
        x0 += bf2f(a.x); y0 += bf2f(a.y); z0 += bf2f(a.z); w0 += bf2f(a.w);
    }
    float4 r; r.x = x0 + x1; r.y = y0 + y1; r.z = z0 + z1; r.w = w0 + w1;
    *(float4*)&aggout[((size_t)node << 6) + (size_t)sl * 4] = r;
}

// Layer-2 aggregation over bf16 P rows (128 B/row): out = ni*sum(P[s]) + b2.
__global__ __launch_bounds__(256) void agg_final(const int* __restrict__ deg_in,
                                                 const int* __restrict__ padded,
                                                 const unsigned short* __restrict__ Pb,
                                                 const float* __restrict__ norm_in,
                                                 const float* __restrict__ b2,
                                                 float* __restrict__ out) {
    const int tid = threadIdx.x;
    const int node = blockIdx.x * 16 + (tid >> 4);
    const int l4 = (tid & 15) * 4;
    if (node >= NNODES) return;
    const int* row = padded + ((size_t)node << 6);
    int n = deg_in[node]; if (n > STRIDE) n = STRIDE;
    float x0 = 0.f, y0 = 0.f, z0 = 0.f, w0 = 0.f;
    float x1 = 0.f, y1 = 0.f, z1 = 0.f, w1 = 0.f;
    int k = 0;
    for (; k + 2 <= n; k += 2) {
        int s0 = row[k], s1 = row[k + 1];
        ushort4 a = *(const ushort4*)&Pb[((size_t)s0 << 6) + l4];
        ushort4 b = *(const ushort4*)&Pb[((size_t)s1 << 6) + l4];
        x0 += bf2f(a.x); y0 += bf2f(a.y); z0 += bf2f(a.z); w0 += bf2f(a.w);
        x1 += bf2f(b.x); y1 += bf2f(b.y); z1 += bf2f(b.z); w1 += bf2f(b.w);
    }
    if (k < n) {
        ushort4 a = *(const ushort4*)&Pb[((size_t)row[k] << 6) + l4];
        x0 += bf2f(a.x); y0 += bf2f(a.y); z0 += bf2f(a.z); w0 += bf2f(a.w);
    }
    float ni = norm_in[node];
    const float4 bb = *(const float4*)&b2[l4];
    float4 r;
    r.x = fmaf(x0 + x1, ni, bb.x);
    r.y = fmaf(y0 + y1, ni, bb.y);
    r.z = fmaf(z0 + z1, ni, bb.z);
    r.w = fmaf(w0 + w1, ni, bb.w);
    *(float4*)&out[((size_t)node << 6) + l4] = r;
}

// ---------------- fused dense, bf16 LDS: P = (relu(AGG*ni @ W1 + b1)*sc) @ W2 ----------------
// LDS all-bf16 phase-union, 25600 B -> 6 blocks/CU (was 49.7 KB -> 3):
//   phase1: As_bf [64] rows of 34 u32 (64 vals + pad)  @u32 0      (2176)
//           Ws_bf [64][128] packed                      @u32 2176   (4096)
//   phase2: Cs_bf [64] rows of 68 u32 (128 vals + pad)  @u32 0      (4352)
//           Ws2_bf[64][64] packed (W2 in 2 row-halves)  @u32 4352   (2048)
__global__ __launch_bounds__(256, 6) void gemm12_bf(const float* __restrict__ AGG,
                                                    const float* __restrict__ W1,
                                                    const float* __restrict__ b1,
                                                    const float* __restrict__ W2,
                                                    const float* __restrict__ norm_in,
                                                    const float* __restrict__ sc,
                                                    unsigned short* __restrict__ Pout) {
    __shared__ unsigned int lds32[6400];   // 25600 B
    uint2* lds64 = (uint2*)lds32;
    const int tid = threadIdx.x;
    const int block0 = blockIdx.x * 64;
    const int cg = tid & 15;
    const int ng = tid >> 4;
    const int ng4 = ng * 4;

    // stage As (bf16-packed) and W1 (bf16-packed)
    for (int i = tid; i < 64 * 32; i += 256) {
        int n = i >> 5, kk = i & 31;
        int gn = block0 + n; if (gn >= NNODES) gn = NNODES - 1;
        const float2 v = *(const float2*)&AGG[(size_t)gn * 64 + kk * 2];
        lds32[n * 34 + kk] = packbf(v.x, v.y);
    }
    for (int i = tid; i < 4096; i += 256) {
        const float2 v = *(const float2*)&W1[i * 2];
        lds32[2176 + i] = packbf(v.x, v.y);
    }
    __syncthreads();

    float acc[4][8];
#pragma unroll
    for (int r = 0; r < 4; ++r)
#pragma unroll
        for (int c = 0; c < 8; ++c) acc[r][c] = 0.0f;

    // phase 1: z = A @ W1 (k unrolled by 2; one u32 read feeds 2 k-steps)
#pragma unroll 4
    for (int k0 = 0; k0 < IN_F; k0 += 2) {
        const int kh = k0 >> 1;
        unsigned int pa[4];
        pa[0] = lds32[(ng4 + 0) * 34 + kh];
        pa[1] = lds32[(ng4 + 1) * 34 + kh];
        pa[2] = lds32[(ng4 + 2) * 34 + kh];
        pa[3] = lds32[(ng4 + 3) * 34 + kh];
        const uint2 qlo0 = lds64[1088 + k0 * 32 + cg];
        const uint2 qhi0 = lds64[1088 + k0 * 32 + 16 + cg];
        const uint2 qlo1 = lds64[1088 + (k0 + 1) * 32 + cg];
        const uint2 qhi1 = lds64[1088 + (k0 + 1) * 32 + 16 + cg];
        float w0[8], w1[8];
        w0[0] = BLO(qlo0.x); w0[1] = BHI(qlo0.x); w0[2] = BLO(qlo0.y); w0[3] = BHI(qlo0.y);
        w0[4] = BLO(qhi0.x); w0[5] = BHI(qhi0.x); w0[6] = BLO(qhi0.y); w0[7] = BHI(qhi0.y);
        w1[0] = BLO(qlo1.x); w1[1] = BHI(qlo1.x); w1[2] = BLO(qlo1.y); w1[3] = BHI(qlo1.y);
        w1[4] = BLO(qhi1.x); w1[5] = BHI(qhi1.x); w1[6] = BLO(qhi1.y); w1[7] = BHI(qhi1.y);
#pragma unroll
        for (int r = 0; r < 4; ++r) {
            const float a0 = BLO(pa[r]);
            const float a1 = BHI(pa[r]);
#pragma unroll
            for (int c = 0; c < 8; ++c)
                acc[r][c] = fmaf(a1, w1[c], fmaf(a0, w0[c], acc[r][c]));
        }
    }
    __syncthreads();   // As/Ws reads done before Cs/Ws2 overwrite

    // epilogue 1 -> Cs (bf16), stage W2 rows 0..63 (bf16)
#pragma unroll
    for (int r = 0; r < 4; ++r) {
        int node = block0 + ng4 + r;
        if (node >= NNODES) node = NNODES - 1;   // harmless dup write in LDS
        const float ni = norm_in[node], s = sc[node];
        float h[8];
#pragma unroll
        for (int c = 0; c < 4; ++c) {
            h[c]     = fmaxf(fmaf(acc[r][c],     ni, b1[cg * 4 + c]),      0.0f) * s;
            h[c + 4] = fmaxf(fmaf(acc[r][c + 4], ni, b1[64 + cg * 4 + c]), 0.0f) * s;
        }
        uint2 lo; lo.x = packbf(h[0], h[1]); lo.y = packbf(h[2], h[3]);
        uint2 hi; hi.x = packbf(h[4], h[5]); hi.y = packbf(h[6], h[7]);
        lds64[(ng4 + r) * 34 + cg]      = lo;   // cols cg*4..+3
        lds64[(ng4 + r) * 34 + 16 + cg] = hi;   // cols 64+cg*4..+3
    }
    for (int i = tid; i < 2048; i += 256) {
        const float2 v = *(const float2*)&W2[i * 2];          // rows 0..63
        lds32[4352 + i] = packbf(v.x, v.y);
    }
    __syncthreads();

    float acc2[4][4];
#pragma unroll
    for (int r = 0; r < 4; ++r)
#pragma unroll
        for (int c = 0; c < 4; ++c) acc2[r][c] = 0.0f;

    // phase 2a: k = 0..63 over Cs cols 0..63
#pragma unroll 4
    for (int k0 = 0; k0 < 64; k0 += 2) {
        const int kh = k0 >> 1;
        unsigned int pc[4];
        pc[0] = lds32[(ng4 + 0) * 68 + kh];
        pc[1] = lds32[(ng4 + 1) * 68 + kh];
        pc[2] = lds32[(ng4 + 2) * 68 + kh];
        pc[3] = lds32[(ng4 + 3) * 68 + kh];
        const uint2 q0 = lds64[2176 + k0 * 16 + cg];
        const uint2 q1 = lds64[2176 + (k0 + 1) * 16 + cg];
        float w0[4], w1[4];
        w0[0] = BLO(q0.x); w0[1] = BHI(q0.x); w0[2] = BLO(q0.y); w0[3] = BHI(q0.y);
        w1[0] = BLO(q1.x); w1[1] = BHI(q1.x); w1[2] = BLO(q1.y); w1[3] = BHI(q1.y);
#pragma unroll
        for (int r = 0; r < 4; ++r) {
            const float a0 = BLO(pc[r]);
            const float a1 = BHI(pc[r]);
#pragma unroll
            for (int c = 0; c < 4; ++c)
                acc2[r][c] = fmaf(a1, w1[c], fmaf(a0, w0[c], acc2[r][c]));
        }
    }
    __syncthreads();
    for (int i = tid; i < 2048; i += 256) {
        const float2 v = *(const float2*)&W2[4096 + i * 2];   // rows 64..127
        lds32[4352 + i] = packbf(v.x, v.y);
    }
    __syncthreads();

    // phase 2b: k = 64..127 over Cs cols 64..127
#pragma unroll 4
    for (int k0 = 0; k0 < 64; k0 += 2) {
        const int kh = k0 >> 1;
        unsigned int pc[4];
        pc[0] = lds32[(ng4 + 0) * 68 + 32 + kh];
        pc[1] = lds32[(ng4 + 1) * 68 + 32 + kh];
        pc[2] = lds32[(ng4 + 2) * 68 + 32 + kh];
        pc[3] = lds32[(ng4 + 3) * 68 + 32 + kh];
        const uint2 q0 = lds64[2176 + k0 * 16 + cg];
        const uint2 q1 = lds64[2176 + (k0 + 1) * 16 + cg];
        float w0[4], w1[4];
        w0[0] = BLO(q0.x); w0[1] = BHI(q0.x); w0[2] = BLO(q0.y); w0[3] = BHI(q0.y);
        w1[0] = BLO(q1.x); w1[1] = BHI(q1.x); w1[2] = BLO(q1.y); w1[3] = BHI(q1.y);
#pragma unroll
        for (int r = 0; r < 4; ++r) {
            const float a0 = BLO(pc[r]);
            const float a1 = BHI(pc[r]);
#pragma unroll
            for (int c = 0; c < 4; ++c)
                acc2[r][c] = fmaf(a1, w1[c], fmaf(a0, w0[c], acc2[r][c]));
        }
    }

#pragma unroll
    for (int r = 0; r < 4; ++r) {
        int node = block0 + ng4 + r;
        if (node >= NNODES) break;
        ushort4 o;
        o.x = f2bf(acc2[r][0]); o.y = f2bf(acc2[r][1]);
        o.z = f2bf(acc2[r][2]); o.w = f2bf(acc2[r][3]);
        *(ushort4*)&Pout[((size_t)node << 6) + cg * 4] = o;
    }
}

// ---------------- launch ----------------

static inline size_t align_up(size_t x, size_t a) { return (x + a - 1) & ~(a - 1); }

extern "C" void kernel_launch(void* const* d_in, const int* in_sizes, int n_in,
                              void* d_out, int out_size, void* d_ws, size_t ws_size,
                              hipStream_t stream) {
    const float* features = (const float*)d_in[0];
    const float* W1       = (const float*)d_in[1];
    const float* b1       = (const float*)d_in[2];
    const float* W2       = (const float*)d_in[3];
    const float* b2       = (const float*)d_in[4];
    const int*   src      = (const int*)d_in[5];
    const int*   dst      = (const int*)d_in[6];
    float* out = (float*)d_out;

    // workspace carve-up — total ~51.9 MB (proven-safe footprint).
    char* ws = (char*)d_ws;
    size_t off = 0;
    int*   bcur     = (int*)(ws + off);   off = align_up(off + 2 * NB * sizeof(int), 256); // [bcur_d | bcur_s]
    size_t zero_bytes = off;
    int*   bcur_d   = bcur;
    int*   bcur_s   = bcur + NB;
    int*   deg_in   = (int*)(ws + off);   off = align_up(off + NNODES * sizeof(int), 256);
    float* norm_in  = (float*)(ws + off); off = align_up(off + NNODES * sizeof(float), 256);
    float* sc       = (float*)(ws + off); off = align_up(off + NNODES * sizeof(float), 256);
    int*   padded   = (int*)(ws + off);   off = align_up(off + (size_t)NNODES * STRIDE * sizeof(int), 256);
    float* AGG      = (float*)(ws + off); off = align_up(off + (size_t)NNODES * IN_F * sizeof(float), 256);
    float* C        = (float*)(ws + off); off = align_up(off + (size_t)NNODES * HID * sizeof(float), 256);
    // aliases inside the 25.6 MB C region:
    //   [0, 4.01MB)    bed  (dst-bucketed edge records, u32) — dead after step 3
    //   [4.2, 5.2MB)   bes  (src-bucketed low-bytes, u8)     — dead after step 3
    //   [8, 14.4MB)    xbf  (bf16 pre-scaled features)       — dead after step 4
    //   [0, 6.4MB)     Pb   (bf16 P, written step 5, read step 6) — reuses dead bed
    unsigned int*   bed = (unsigned int*)C;
    unsigned char*  bes = (unsigned char*)((char*)C + align_up((size_t)NB * BCAP * 4, 256));
    unsigned short* xbf = (unsigned short*)((char*)C + (8u << 20));
    unsigned short* Pb  = (unsigned short*)C;
    (void)ws_size; (void)out_size; (void)n_in; (void)in_sizes;

    const int B256 = 256;

    // 1. zero bucket cursors (2 KB)
    hipMemsetAsync(bcur, 0, zero_bytes, stream);
    // 2. bucket all edges by dst (CSR) and by src (out-degree)
    bucket_edges_k<<<(NEDGES + CHUNK - 1) / CHUNK, B256, 0, stream>>>(src, dst, bcur_d, bcur_s, bed, bes);
    // 3. per-bucket: padded CSR + degrees + norms + xbf = bf16(feat*sc)
    csr_norm_xpre<<<NB, B256, 0, stream>>>(bcur_d, bcur_s, bed, bes, features,
                                           padded, deg_in, norm_in, sc, xbf);
    // 4. layer-1 aggregation over bf16 rows: AGG[i] = sum xbf[s]
    agg_xpre<<<(NNODES + 15) / 16, B256, 0, stream>>>(deg_in, padded, xbf, AGG);
    // 5. fused dense (bf16 LDS): Pb = bf16( (relu(AGG*ni @ W1 + b1)*sc) @ W2 )
    gemm12_bf<<<(NNODES + 63) / 64, B256, 0, stream>>>(AGG, W1, b1, W2, norm_in, sc, Pb);
    // 6. layer-2 aggregation + finalize: out = (sum Pb[s]) * ni + b2
    agg_final<<<(NNODES + 15) / 16, B256, 0, stream>>>(deg_in, padded, Pb, norm_in, b2, out);
}